// Round 4
// baseline (411.225 us; speedup 1.0000x reference)
//
#include <hip/hip_runtime.h>

typedef short s16x8 __attribute__((ext_vector_type(8)));
typedef short s16x4 __attribute__((ext_vector_type(4)));
typedef float f32x4 __attribute__((ext_vector_type(4)));
typedef float f4 __attribute__((ext_vector_type(4)));
typedef unsigned short u16x4 __attribute__((ext_vector_type(4)));

#define CEXP 14.426950408889634074f   // 10 * log2(e)

__device__ __forceinline__ unsigned short f2bf(float f) {
    union { float f; unsigned int i; } v; v.f = f;
    unsigned int x = v.i;
    return (unsigned short)((x + 0x7fffu + ((x >> 16) & 1u)) >> 16);  // RNE
}
__device__ __forceinline__ float bf2f(unsigned short u) {
    union { unsigned int i; float f; } v; v.i = ((unsigned int)u) << 16; return v.f;
}

// PV matrix op: D = A*B + C with K=16; B k-index layout (k = 4*quad + e)
// matches the C/D row layout of the 16x16x32 QK MFMA, so P needs no
// cross-lane transpose at all.
__device__ __forceinline__ f32x4 mfma16x16x16_bf16(s16x4 a, s16x4 b, f32x4 c) {
#if __has_builtin(__builtin_amdgcn_mfma_f32_16x16x16bf16_1k)
    return __builtin_amdgcn_mfma_f32_16x16x16bf16_1k(a, b, c, 0, 0, 0);
#else
    f32x4 d = c;
    asm("v_mfma_f32_16x16x16_bf16 %0, %1, %2, %0" : "+v"(d) : "v"(a), "v"(b));
    return d;
#endif
}

// ---------------------------------------------------------------------------
// k_qkv: qkv = x @ W_qkv  (M=16384, K=128, N=384), fp32 compute.
// cb=0 -> q (bf16, unscaled, [bh][N][32]) + sumsq atomics
// cb=1 -> k (same)
// cb=2 -> v (bf16, transposed [bh][32][N])
// ---------------------------------------------------------------------------
__global__ __launch_bounds__(256, 3) void k_qkv(
    const float* __restrict__ x, const float* __restrict__ Wqkv,
    unsigned short* __restrict__ Qb, unsigned short* __restrict__ Kb,
    unsigned short* __restrict__ Vt, float* __restrict__ sumsq)
{
    __shared__ float xs[64][68];
    __shared__ float wsl[64][128];
    const int tb = blockIdx.x, cb = blockIdx.y;
    const int tid = threadIdx.x, tx = tid & 15, ty = tid >> 4;
    float acc[4][8];
#pragma unroll
    for (int t = 0; t < 4; ++t)
#pragma unroll
        for (int j = 0; j < 8; ++j) acc[t][j] = 0.f;

    for (int kc = 0; kc < 2; ++kc) {
        __syncthreads();
#pragma unroll
        for (int s = 0; s < 4; ++s) {
            int slot = tid + s * 256;
            int r = slot >> 4, c4 = (slot & 15) << 2;
            *(f4*)&xs[r][c4] = *(const f4*)&x[(tb * 64 + r) * 128 + kc * 64 + c4];
        }
#pragma unroll
        for (int s = 0; s < 8; ++s) {
            int slot = tid + s * 256;
            int r = slot >> 5, c4 = (slot & 31) << 2;
            *(f4*)&wsl[r][c4] = *(const f4*)&Wqkv[(kc * 64 + r) * 384 + cb * 128 + c4];
        }
        __syncthreads();
        for (int e = 0; e < 64; ++e) {
            f4 b0 = *(const f4*)&wsl[e][tx * 4];
            f4 b1 = *(const f4*)&wsl[e][64 + tx * 4];
#pragma unroll
            for (int t = 0; t < 4; ++t) {
                float a = xs[ty * 4 + t][e];
#pragma unroll
                for (int j = 0; j < 4; ++j) {
                    acc[t][j]     += a * b0[j];
                    acc[t][4 + j] += a * b1[j];
                }
            }
        }
    }

    const int b = tb >> 6;                    // 64 token-blocks per batch
    const int n0 = (tb & 63) * 64 + ty * 4;   // n within batch
    if (cb < 2) {
        unsigned short* dst = (cb == 0) ? Qb : Kb;
#pragma unroll
        for (int g = 0; g < 2; ++g) {
            int c = g * 64 + tx * 4;
            int h = c >> 5, d = c & 31;
#pragma unroll
            for (int t = 0; t < 4; ++t) {
                u16x4 pk = { f2bf(acc[t][g * 4 + 0]), f2bf(acc[t][g * 4 + 1]),
                             f2bf(acc[t][g * 4 + 2]), f2bf(acc[t][g * 4 + 3]) };
                *(u16x4*)&dst[(size_t)(((b * 4 + h) * 4096) + n0 + t) * 32 + d] = pk;
            }
#pragma unroll
            for (int j = 0; j < 4; ++j) {
                float ss = 0.f;
#pragma unroll
                for (int t = 0; t < 4; ++t) ss += acc[t][g * 4 + j] * acc[t][g * 4 + j];
                ss += __shfl_xor(ss, 16);
                ss += __shfl_xor(ss, 32);
                if ((ty & 3) == 0)
                    atomicAdd(&sumsq[cb * 512 + (b * 4 + h) * 32 + d + j], ss);
            }
        }
    } else {
#pragma unroll
        for (int g = 0; g < 2; ++g) {
            int c = g * 64 + tx * 4;
            int h = c >> 5, d0 = c & 31;
#pragma unroll
            for (int j = 0; j < 4; ++j) {
                u16x4 pk = { f2bf(acc[0][g * 4 + j]), f2bf(acc[1][g * 4 + j]),
                             f2bf(acc[2][g * 4 + j]), f2bf(acc[3][g * 4 + j]) };
                *(u16x4*)&Vt[(size_t)((b * 4 + h) * 32 + d0 + j) * 4096 + n0] = pk;
            }
        }
    }
}

// ---------------------------------------------------------------------------
// k_norm: in-place scale of Qb/Kb by min(rsqrt(sumsq), 1e12).
// Q additionally gets the softmax scale 10*log2(e) folded in, so k_attn's
// QK^T MFMA directly produces log2-domain logits.
// ---------------------------------------------------------------------------
__global__ __launch_bounds__(256) void k_norm(
    unsigned short* __restrict__ Qb, unsigned short* __restrict__ Kb,
    const float* __restrict__ sumsq)
{
    int t = blockIdx.x * 256 + threadIdx.x;   // 524288 threads, 8 elems each
    int which = t >> 18;
    int ti = t & 0x3ffff;
    unsigned short* arr = which ? Kb : Qb;
    const float post = which ? 1.0f : CEXP;
    int i8 = ti * 8;
    int d0 = i8 & 31;
    int bh = i8 >> 17;                        // 4096*32 elements per bh
    const float* sq = sumsq + which * 512 + bh * 32 + d0;
    union { uint4 v; unsigned short u[8]; } dat;
    dat.v = *(const uint4*)(arr + i8);
#pragma unroll
    for (int j = 0; j < 8; ++j) {
        float r = fminf(__builtin_amdgcn_rsqf(sq[j]), 1e12f) * post;
        dat.u[j] = f2bf(bf2f(dat.u[j]) * r);
    }
    *(uint4*)(arr + i8) = dat.v;
}

// ---------------------------------------------------------------------------
// k_attn: flash attention per (bh).  Block = 64 q-rows (4 waves x 16 rows).
// Inner loop has NO LDS, NO barriers, NO shuffles:
//   - S^T via mfma_16x16x32 (A=K rows from global, B=Q): lane holds
//     S[i=nn][j=jb+16js+4qd+r] in C layout.
//   - P packed to bf16 in-register; C row layout (4qd+r) == B k-layout of
//     mfma_16x16x16 (4qd+e), so PV runs directly: O^T += V^T_frag * P.
//   - l accumulated per-lane, shuffle-reduced once after the loop.
//   - K and V fragments for iteration jt+1 prefetched during jt (reads one
//     tile past the end stay inside d_ws).
// Grid (bh=16, itile=64): linear id % 8 == bh % 8, so each XCD sees ~2 bh
// (1 MB of K+V) -> L2-resident.
// ---------------------------------------------------------------------------
__global__ __launch_bounds__(256, 4) void k_attn(
    const unsigned short* __restrict__ Qb, const unsigned short* __restrict__ Kb,
    const unsigned short* __restrict__ Vt, float* __restrict__ Og)
{
    __shared__ float epi[4][576];
    const int tid = threadIdx.x;
    const int wv = tid >> 6, lane = tid & 63;
    const int qd = lane >> 4, nn = lane & 15;
    const int bh = blockIdx.x;
    const int ib = blockIdx.y * 64 + wv * 16;
    const unsigned short* Qbh = Qb + (size_t)bh * 4096 * 32;
    const unsigned short* Kbh = Kb + (size_t)bh * 4096 * 32;
    const unsigned short* Vbh = Vt + (size_t)bh * 32 * 4096;

    s16x8 qfrag = *(const s16x8*)(Qbh + (ib + nn) * 32 + qd * 8);
    f32x4 o0 = {0.f, 0.f, 0.f, 0.f}, o1 = {0.f, 0.f, 0.f, 0.f};
    const f32x4 zro = {0.f, 0.f, 0.f, 0.f};
    float lp = 0.f;

    const unsigned short* kp  = Kbh + nn * 32 + qd * 8;             // += 2048/iter
    const unsigned short* vp0 = Vbh + (size_t)nn * 4096 + qd * 4;   // += 64/iter
    const unsigned short* vp1 = Vbh + (size_t)(16 + nn) * 4096 + qd * 4;

    s16x8 kf[4];
    s16x4 va[4], vb[4];
#pragma unroll
    for (int js = 0; js < 4; ++js) {
        kf[js] = *(const s16x8*)(kp + js * 512);
        va[js] = *(const s16x4*)(vp0 + js * 16);
        vb[js] = *(const s16x4*)(vp1 + js * 16);
    }

    for (int jt = 0; jt < 64; ++jt) {
        kp += 2048; vp0 += 64; vp1 += 64;
        s16x8 kn[4];
        s16x4 van[4], vbn[4];
#pragma unroll
        for (int js = 0; js < 4; ++js) {              // prefetch jt+1
            kn[js]  = *(const s16x8*)(kp + js * 512);
            van[js] = *(const s16x4*)(vp0 + js * 16);
            vbn[js] = *(const s16x4*)(vp1 + js * 16);
        }
        f32x4 sv[4];
#pragma unroll
        for (int js = 0; js < 4; ++js)
            sv[js] = __builtin_amdgcn_mfma_f32_16x16x32_bf16(kf[js], qfrag, zro, 0, 0, 0);
#pragma unroll
        for (int js = 0; js < 4; ++js) {
            float p0 = __builtin_amdgcn_exp2f(sv[js][0]);
            float p1 = __builtin_amdgcn_exp2f(sv[js][1]);
            float p2 = __builtin_amdgcn_exp2f(sv[js][2]);
            float p3 = __builtin_amdgcn_exp2f(sv[js][3]);
            lp += (p0 + p1) + (p2 + p3);
            // round-half-up bf16 pack; element order == k order (4qd+e)
            unsigned u0 = __float_as_uint(p0) + 0x8000u;
            unsigned u1 = __float_as_uint(p1) + 0x8000u;
            unsigned u2 = __float_as_uint(p2) + 0x8000u;
            unsigned u3 = __float_as_uint(p3) + 0x8000u;
            union { uint2 u; s16x4 s; } pb;
            pb.u.x = __builtin_amdgcn_perm(u1, u0, 0x07060302u);  // [p0,p1]
            pb.u.y = __builtin_amdgcn_perm(u3, u2, 0x07060302u);  // [p2,p3]
            o0 = mfma16x16x16_bf16(va[js], pb.s, o0);
            o1 = mfma16x16x16_bf16(vb[js], pb.s, o1);
        }
#pragma unroll
        for (int js = 0; js < 4; ++js) { kf[js] = kn[js]; va[js] = van[js]; vb[js] = vbn[js]; }
    }
    lp += __shfl_xor(lp, 16);
    lp += __shfl_xor(lp, 32);
    float rl = 1.f / lp;
    o0 *= rl;
    o1 *= rl;
    float* ep = epi[wv];                   // per-wave region; no cross-wave hazard
#pragma unroll
    for (int r = 0; r < 4; ++r) {
        ep[nn * 36 + qd * 4 + r]      = o0[r];   // O[i=nn][dd=4*qd+r]
        ep[nn * 36 + 16 + qd * 4 + r] = o1[r];   // O[i=nn][dd=16+4*qd+r]
    }
    const int i = lane >> 2, c8 = (lane & 3) * 8;
    f4 w0 = *(const f4*)&ep[i * 36 + c8];
    f4 w1 = *(const f4*)&ep[i * 36 + c8 + 4];
    const int bb = bh >> 2, hh = bh & 3;
    float* dst = Og + (size_t)(bb * 4096 + blockIdx.y * 64 + wv * 16 + i) * 128 + hh * 32 + c8;
    *(f4*)dst = w0;
    *(f4*)(dst + 4) = w1;
}

// ---------------------------------------------------------------------------
// k_out: out = Og @ W_out + b_out  (M=16384, K=128, N=128), fp32.
// ---------------------------------------------------------------------------
__global__ __launch_bounds__(256, 3) void k_out(
    const float* __restrict__ Og, const float* __restrict__ Wout,
    const float* __restrict__ bout, float* __restrict__ out)
{
    __shared__ float xs[64][68];
    __shared__ float wsl[64][128];
    const int tb = blockIdx.x;
    const int tid = threadIdx.x, tx = tid & 15, ty = tid >> 4;
    float acc[4][8];
#pragma unroll
    for (int t = 0; t < 4; ++t)
#pragma unroll
        for (int j = 0; j < 8; ++j) acc[t][j] = 0.f;

    for (int kc = 0; kc < 2; ++kc) {
        __syncthreads();
#pragma unroll
        for (int s = 0; s < 4; ++s) {
            int slot = tid + s * 256;
            int r = slot >> 4, c4 = (slot & 15) << 2;
            *(f4*)&xs[r][c4] = *(const f4*)&Og[(size_t)(tb * 64 + r) * 128 + kc * 64 + c4];
        }
#pragma unroll
        for (int s = 0; s < 8; ++s) {
            int slot = tid + s * 256;
            int r = slot >> 5, c4 = (slot & 31) << 2;
            *(f4*)&wsl[r][c4] = *(const f4*)&Wout[(kc * 64 + r) * 128 + c4];
        }
        __syncthreads();
        for (int e = 0; e < 64; ++e) {
            f4 b0 = *(const f4*)&wsl[e][tx * 4];
            f4 b1 = *(const f4*)&wsl[e][64 + tx * 4];
#pragma unroll
            for (int t = 0; t < 4; ++t) {
                float a = xs[ty * 4 + t][e];
#pragma unroll
                for (int j = 0; j < 4; ++j) {
                    acc[t][j]     += a * b0[j];
                    acc[t][4 + j] += a * b1[j];
                }
            }
        }
    }
    f4 bv0 = *(const f4*)&bout[tx * 4];
    f4 bv1 = *(const f4*)&bout[64 + tx * 4];
#pragma unroll
    for (int t = 0; t < 4; ++t) {
        f4 r0, r1;
#pragma unroll
        for (int j = 0; j < 4; ++j) { r0[j] = acc[t][j] + bv0[j]; r1[j] = acc[t][4 + j] + bv1[j]; }
        float* o = out + (size_t)(tb * 64 + ty * 4 + t) * 128;
        *(f4*)(o + tx * 4) = r0;
        *(f4*)(o + 64 + tx * 4) = r1;
    }
}

// ---------------------------------------------------------------------------
extern "C" void kernel_launch(void* const* d_in, const int* in_sizes, int n_in,
                              void* d_out, int out_size, void* d_ws, size_t ws_size,
                              hipStream_t stream)
{
    const float* x    = (const float*)d_in[0];
    const float* Wqkv = (const float*)d_in[1];
    const float* Wout = (const float*)d_in[2];
    const float* bout = (const float*)d_in[3];
    float* out = (float*)d_out;
    char* ws = (char*)d_ws;
    const size_t MB = 1024 * 1024;
    unsigned short* Qb = (unsigned short*)(ws);             // 4 MB  [16][4096][32] bf16
    unsigned short* Kb = (unsigned short*)(ws + 4 * MB);    // 4 MB
    unsigned short* Vt = (unsigned short*)(ws + 8 * MB);    // 4 MB  [16][32][4096] bf16
    float*          Og = (float*)(ws + 12 * MB);            // 8 MB  [16384][128] fp32
    float*       sumsq = (float*)(ws + 20 * MB);            // 4 KB  [2][16][32] fp32

    hipMemsetAsync(sumsq, 0, 4096, stream);
    hipLaunchKernelGGL(k_qkv, dim3(256, 3), dim3(256), 0, stream, x, Wqkv, Qb, Kb, Vt, sumsq);
    hipLaunchKernelGGL(k_norm, dim3(2048), dim3(256), 0, stream, Qb, Kb, sumsq);
    hipLaunchKernelGGL(k_attn, dim3(16, 64), dim3(256), 0, stream, Qb, Kb, Vt, Og);
    hipLaunchKernelGGL(k_out, dim3(256), dim3(256), 0, stream, Og, Wout, bout, out);
}

// Round 6
// 200.340 us; speedup vs baseline: 2.0526x; 2.0526x over previous
//
#include <hip/hip_runtime.h>

typedef short s16x8 __attribute__((ext_vector_type(8)));
typedef short s16x4 __attribute__((ext_vector_type(4)));
typedef float f32x4 __attribute__((ext_vector_type(4)));
typedef float f4 __attribute__((ext_vector_type(4)));
typedef unsigned short u16x4 __attribute__((ext_vector_type(4)));

#define CEXP 14.426950408889634074f   // 10 * log2(e)

__device__ __forceinline__ unsigned short f2bf(float f) {
    union { float f; unsigned int i; } v; v.f = f;
    unsigned int x = v.i;
    return (unsigned short)((x + 0x7fffu + ((x >> 16) & 1u)) >> 16);  // RNE
}
__device__ __forceinline__ float bf2f(unsigned short u) {
    union { unsigned int i; float f; } v; v.i = ((unsigned int)u) << 16; return v.f;
}

// PV matrix op: D = A*B + C with K=16; B k-index layout (k = 4*quad + e)
// matches the C/D row layout of the 16x16x32 QK MFMA (validated: R4 passed).
__device__ __forceinline__ f32x4 mfma16x16x16_bf16(s16x4 a, s16x4 b, f32x4 c) {
#if __has_builtin(__builtin_amdgcn_mfma_f32_16x16x16bf16_1k)
    return __builtin_amdgcn_mfma_f32_16x16x16bf16_1k(a, b, c, 0, 0, 0);
#else
    f32x4 d = c;
    asm("v_mfma_f32_16x16x16_bf16 %0, %1, %2, %0" : "+v"(d) : "v"(a), "v"(b));
    return d;
#endif
}

// ---------------------------------------------------------------------------
// k_qkv: qkv = x @ W_qkv  (M=16384, K=128, N=384), fp32 compute.
// ---------------------------------------------------------------------------
__global__ __launch_bounds__(256, 3) void k_qkv(
    const float* __restrict__ x, const float* __restrict__ Wqkv,
    unsigned short* __restrict__ Qb, unsigned short* __restrict__ Kb,
    unsigned short* __restrict__ Vt, float* __restrict__ sumsq)
{
    __shared__ float xs[64][68];
    __shared__ float wsl[64][128];
    const int tb = blockIdx.x, cb = blockIdx.y;
    const int tid = threadIdx.x, tx = tid & 15, ty = tid >> 4;
    float acc[4][8];
#pragma unroll
    for (int t = 0; t < 4; ++t)
#pragma unroll
        for (int j = 0; j < 8; ++j) acc[t][j] = 0.f;

    for (int kc = 0; kc < 2; ++kc) {
        __syncthreads();
#pragma unroll
        for (int s = 0; s < 4; ++s) {
            int slot = tid + s * 256;
            int r = slot >> 4, c4 = (slot & 15) << 2;
            *(f4*)&xs[r][c4] = *(const f4*)&x[(tb * 64 + r) * 128 + kc * 64 + c4];
        }
#pragma unroll
        for (int s = 0; s < 8; ++s) {
            int slot = tid + s * 256;
            int r = slot >> 5, c4 = (slot & 31) << 2;
            *(f4*)&wsl[r][c4] = *(const f4*)&Wqkv[(kc * 64 + r) * 384 + cb * 128 + c4];
        }
        __syncthreads();
        for (int e = 0; e < 64; ++e) {
            f4 b0 = *(const f4*)&wsl[e][tx * 4];
            f4 b1 = *(const f4*)&wsl[e][64 + tx * 4];
#pragma unroll
            for (int t = 0; t < 4; ++t) {
                float a = xs[ty * 4 + t][e];
#pragma unroll
                for (int j = 0; j < 4; ++j) {
                    acc[t][j]     += a * b0[j];
                    acc[t][4 + j] += a * b1[j];
                }
            }
        }
    }

    const int b = tb >> 6;
    const int n0 = (tb & 63) * 64 + ty * 4;
    if (cb < 2) {
        unsigned short* dst = (cb == 0) ? Qb : Kb;
#pragma unroll
        for (int g = 0; g < 2; ++g) {
            int c = g * 64 + tx * 4;
            int h = c >> 5, d = c & 31;
#pragma unroll
            for (int t = 0; t < 4; ++t) {
                u16x4 pk = { f2bf(acc[t][g * 4 + 0]), f2bf(acc[t][g * 4 + 1]),
                             f2bf(acc[t][g * 4 + 2]), f2bf(acc[t][g * 4 + 3]) };
                *(u16x4*)&dst[(size_t)(((b * 4 + h) * 4096) + n0 + t) * 32 + d] = pk;
            }
#pragma unroll
            for (int j = 0; j < 4; ++j) {
                float ss = 0.f;
#pragma unroll
                for (int t = 0; t < 4; ++t) ss += acc[t][g * 4 + j] * acc[t][g * 4 + j];
                ss += __shfl_xor(ss, 16);
                ss += __shfl_xor(ss, 32);
                if ((ty & 3) == 0)
                    atomicAdd(&sumsq[cb * 512 + (b * 4 + h) * 32 + d + j], ss);
            }
        }
    } else {
#pragma unroll
        for (int g = 0; g < 2; ++g) {
            int c = g * 64 + tx * 4;
            int h = c >> 5, d0 = c & 31;
#pragma unroll
            for (int j = 0; j < 4; ++j) {
                u16x4 pk = { f2bf(acc[0][g * 4 + j]), f2bf(acc[1][g * 4 + j]),
                             f2bf(acc[2][g * 4 + j]), f2bf(acc[3][g * 4 + j]) };
                *(u16x4*)&Vt[(size_t)((b * 4 + h) * 32 + d0 + j) * 4096 + n0] = pk;
            }
        }
    }
}

// ---------------------------------------------------------------------------
// k_norm: scale Qb/Kb by min(rsqrt(sumsq), 1e12); Q also gets 10*log2(e).
// ---------------------------------------------------------------------------
__global__ __launch_bounds__(256) void k_norm(
    unsigned short* __restrict__ Qb, unsigned short* __restrict__ Kb,
    const float* __restrict__ sumsq)
{
    int t = blockIdx.x * 256 + threadIdx.x;
    int which = t >> 18;
    int ti = t & 0x3ffff;
    unsigned short* arr = which ? Kb : Qb;
    const float post = which ? 1.0f : CEXP;
    int i8 = ti * 8;
    int d0 = i8 & 31;
    int bh = i8 >> 17;
    const float* sq = sumsq + which * 512 + bh * 32 + d0;
    union { uint4 v; unsigned short u[8]; } dat;
    dat.v = *(const uint4*)(arr + i8);
#pragma unroll
    for (int j = 0; j < 8; ++j) {
        float r = fminf(__builtin_amdgcn_rsqf(sq[j]), 1e12f) * post;
        dat.u[j] = f2bf(bf2f(dat.u[j]) * r);
    }
    *(uint4*)(arr + i8) = dat.v;
}

// ---------------------------------------------------------------------------
// k_attn v4: 512 threads = 8 waves; waves 0-3 j in [0,2048), waves 4-7 j in
// [2048,4096); linear merge (no online max needed, |logits| << 1).
// Staging: EXPLICIT global_load_dwordx4 -> VGPR -> ds_write_b128, double
// buffered, one barrier per iteration.  (R5's global_load_lds DMA produced
// NaN = stale-LDS reads -> its lane->LDS mapping didn't match the model;
// explicit ds_write has fully architected semantics.)  The global load's
// consumer (ds_write) sits at iteration END, so the compute phase hides the
// ~250cy L2 latency regardless of where the compiler schedules the waitcnt
// (the R3/R4 failure was loads sunk into the *critical* chain).
// LDS K layout: [row jt16+nn][chunk qd] at (js*1024 + lane*16) -> reads are
// contiguous 1KB/wave, conflict-free.  V layout gives 2-way max (free).
// ---------------------------------------------------------------------------
__global__ __launch_bounds__(512, 4) void k_attn(
    const unsigned short* __restrict__ Qb, const unsigned short* __restrict__ Kb,
    const unsigned short* __restrict__ Vt, float* __restrict__ Og)
{
    __shared__ char smem[32768];
    const int tid  = threadIdx.x;
    const int wv   = tid >> 6, lane = tid & 63;
    const int wl   = wv & 3, half = wv >> 2;
    const int qd   = lane >> 4, nn = lane & 15;
    const int bh   = blockIdx.x;
    const int ib   = blockIdx.y * 64 + wl * 16;
    const unsigned short* Qbh = Qb + (size_t)bh * 4096 * 32;
    const unsigned short* Kbh = Kb + (size_t)bh * 4096 * 32;
    const unsigned short* Vbh = Vt + (size_t)bh * 32 * 4096;

    s16x8 qfrag = *(const s16x8*)(Qbh + (ib + nn) * 32 + qd * 8);
    f32x4 o0 = {0.f,0.f,0.f,0.f}, o1 = {0.f,0.f,0.f,0.f};
    const f32x4 zro = {0.f,0.f,0.f,0.f};
    float lp = 0.f;

    const int KB0 = half * 8192;           // 2 x 4KB K buffers for this half
    const int VB0 = 16384 + half * 8192;   // 2 x 4KB V buffers for this half
    const int jb0 = half * 2048;

    // per-lane global sources (16B each; advance per tile)
    const unsigned short* ksrc = Kbh + (size_t)(jb0 + wl * 16 + nn) * 32 + qd * 8;
    const unsigned short* vsrc = Vbh + (size_t)(nn + 16 * (wl >> 1)) * 4096
                               + jb0 + ((wl & 1) * 2 + (qd >> 1)) * 16 + (qd & 1) * 8;
    // per-lane LDS staging slots (lane-contiguous: base + lane*16)
    char* kdst = smem + KB0 + wl * 1024 + lane * 16;
    char* vdst = smem + VB0 + wl * 1024 + lane * 16;

    {   // preload tile 0 -> buffer 0
        uint4 gk = *(const uint4*)ksrc;
        uint4 gv = *(const uint4*)vsrc;
        ksrc += 2048; vsrc += 64;
        *(uint4*)kdst = gk;
        *(uint4*)vdst = gv;
    }

    const int vro = (qd >> 1) * 256 + nn * 16 + (qd & 1) * 8;

    for (int jt = 0; jt < 32; ++jt) {
        uint4 ngk = *(const uint4*)ksrc;     // tile jt+1 (jt=31: in-ws, unused)
        uint4 ngv = *(const uint4*)vsrc;
        ksrc += 2048; vsrc += 64;

        __syncthreads();                     // tile jt visible in buf[jt&1]
        const char* kcur = smem + KB0 + (jt & 1) * 4096;
        const char* vcur = smem + VB0 + (jt & 1) * 4096;
#pragma unroll
        for (int js = 0; js < 4; ++js) {
            s16x8 kf = *(const s16x8*)(kcur + js * 1024 + lane * 16);
            f32x4 sv = __builtin_amdgcn_mfma_f32_16x16x32_bf16(kf, qfrag, zro, 0, 0, 0);
            float p0 = __builtin_amdgcn_exp2f(sv[0]);
            float p1 = __builtin_amdgcn_exp2f(sv[1]);
            float p2 = __builtin_amdgcn_exp2f(sv[2]);
            float p3 = __builtin_amdgcn_exp2f(sv[3]);
            lp += (p0 + p1) + (p2 + p3);
            unsigned u0 = __float_as_uint(p0) + 0x8000u;
            unsigned u1 = __float_as_uint(p1) + 0x8000u;
            unsigned u2 = __float_as_uint(p2) + 0x8000u;
            unsigned u3 = __float_as_uint(p3) + 0x8000u;
            union { uint2 u; s16x4 s; } pb;
            pb.u.x = __builtin_amdgcn_perm(u1, u0, 0x07060302u);
            pb.u.y = __builtin_amdgcn_perm(u3, u2, 0x07060302u);
            s16x4 va = *(const s16x4*)(vcur + js * 512 + vro);
            s16x4 vb = *(const s16x4*)(vcur + 2048 + js * 512 + vro);
            o0 = mfma16x16x16_bf16(va, pb.s, o0);
            o1 = mfma16x16x16_bf16(vb, pb.s, o1);
        }
        // stage tile jt+1 into the other buffer (safe: buf[nxt] reads all
        // completed before the barrier above, disjoint from buf[jt&1] reads)
        const int nxt4k = ((jt + 1) & 1) * 4096;
        *(uint4*)(kdst + nxt4k) = ngk;
        *(uint4*)(vdst + nxt4k) = ngv;
    }

    lp += __shfl_xor(lp, 16);
    lp += __shfl_xor(lp, 32);
    __syncthreads();                           // all staging traffic drained
    float* Ob = (float*)smem;                  // [4][64][8]
    float* Lb = (float*)(smem + 8192);         // [4][64]
    if (half) {
        float* d = Ob + (wl * 64 + lane) * 8;
        *(f4*)d = o0; *(f4*)(d + 4) = o1;
        Lb[wl * 64 + lane] = lp;
    }
    __syncthreads();
    if (!half) {
        float* d = Ob + (wl * 64 + lane) * 8;
        f4 a0 = *(const f4*)d, a1 = *(const f4*)(d + 4);
        float rl = 1.f / (lp + Lb[wl * 64 + lane]);
        o0 = (o0 + a0) * rl;
        o1 = (o1 + a1) * rl;
        float* ep = (float*)(smem + 9216) + wl * 576;   // [16 i][36]
#pragma unroll
        for (int r = 0; r < 4; ++r) {
            ep[nn * 36 + qd * 4 + r]      = o0[r];
            ep[nn * 36 + 16 + qd * 4 + r] = o1[r];
        }
        const int i = lane >> 2, c8 = (lane & 3) * 8;
        f4 w0 = *(const f4*)&ep[i * 36 + c8];
        f4 w1 = *(const f4*)&ep[i * 36 + c8 + 4];
        const int bb = bh >> 2, hh = bh & 3;
        float* dst = Og + (size_t)(bb * 4096 + blockIdx.y * 64 + wl * 16 + i) * 128 + hh * 32 + c8;
        *(f4*)dst = w0;
        *(f4*)(dst + 4) = w1;
    }
}

// ---------------------------------------------------------------------------
// k_out: out = Og @ W_out + b_out  (M=16384, K=128, N=128), fp32.
// ---------------------------------------------------------------------------
__global__ __launch_bounds__(256, 3) void k_out(
    const float* __restrict__ Og, const float* __restrict__ Wout,
    const float* __restrict__ bout, float* __restrict__ out)
{
    __shared__ float xs[64][68];
    __shared__ float wsl[64][128];
    const int tb = blockIdx.x;
    const int tid = threadIdx.x, tx = tid & 15, ty = tid >> 4;
    float acc[4][8];
#pragma unroll
    for (int t = 0; t < 4; ++t)
#pragma unroll
        for (int j = 0; j < 8; ++j) acc[t][j] = 0.f;

    for (int kc = 0; kc < 2; ++kc) {
        __syncthreads();
#pragma unroll
        for (int s = 0; s < 4; ++s) {
            int slot = tid + s * 256;
            int r = slot >> 4, c4 = (slot & 15) << 2;
            *(f4*)&xs[r][c4] = *(const f4*)&Og[(size_t)(tb * 64 + r) * 128 + kc * 64 + c4];
        }
#pragma unroll
        for (int s = 0; s < 8; ++s) {
            int slot = tid + s * 256;
            int r = slot >> 5, c4 = (slot & 31) << 2;
            *(f4*)&wsl[r][c4] = *(const f4*)&Wout[(kc * 64 + r) * 128 + c4];
        }
        __syncthreads();
        for (int e = 0; e < 64; ++e) {
            f4 b0 = *(const f4*)&wsl[e][tx * 4];
            f4 b1 = *(const f4*)&wsl[e][64 + tx * 4];
#pragma unroll
            for (int t = 0; t < 4; ++t) {
                float a = xs[ty * 4 + t][e];
#pragma unroll
                for (int j = 0; j < 4; ++j) {
                    acc[t][j]     += a * b0[j];
                    acc[t][4 + j] += a * b1[j];
                }
            }
        }
    }
    f4 bv0 = *(const f4*)&bout[tx * 4];
    f4 bv1 = *(const f4*)&bout[64 + tx * 4];
#pragma unroll
    for (int t = 0; t < 4; ++t) {
        f4 r0, r1;
#pragma unroll
        for (int j = 0; j < 4; ++j) { r0[j] = acc[t][j] + bv0[j]; r1[j] = acc[t][4 + j] + bv1[j]; }
        float* o = out + (size_t)(tb * 64 + ty * 4 + t) * 128;
        *(f4*)(o + tx * 4) = r0;
        *(f4*)(o + 64 + tx * 4) = r1;
    }
}

// ---------------------------------------------------------------------------
extern "C" void kernel_launch(void* const* d_in, const int* in_sizes, int n_in,
                              void* d_out, int out_size, void* d_ws, size_t ws_size,
                              hipStream_t stream)
{
    const float* x    = (const float*)d_in[0];
    const float* Wqkv = (const float*)d_in[1];
    const float* Wout = (const float*)d_in[2];
    const float* bout = (const float*)d_in[3];
    float* out = (float*)d_out;
    char* ws = (char*)d_ws;
    const size_t MB = 1024 * 1024;
    unsigned short* Qb = (unsigned short*)(ws);             // 4 MB
    unsigned short* Kb = (unsigned short*)(ws + 4 * MB);    // 4 MB
    unsigned short* Vt = (unsigned short*)(ws + 8 * MB);    // 4 MB
    float*          Og = (float*)(ws + 12 * MB);            // 8 MB
    float*       sumsq = (float*)(ws + 20 * MB);            // 4 KB

    hipMemsetAsync(sumsq, 0, 4096, stream);
    hipLaunchKernelGGL(k_qkv, dim3(256, 3), dim3(256), 0, stream, x, Wqkv, Qb, Kb, Vt, sumsq);
    hipLaunchKernelGGL(k_norm, dim3(2048), dim3(256), 0, stream, Qb, Kb, sumsq);
    hipLaunchKernelGGL(k_attn, dim3(16, 64), dim3(512), 0, stream, Qb, Kb, Vt, Og);
    hipLaunchKernelGGL(k_out, dim3(256), dim3(256), 0, stream, Og, Wout, bout, out);
}

// Round 7
// 169.112 us; speedup vs baseline: 2.4317x; 1.1847x over previous
//
#include <hip/hip_runtime.h>

typedef short s16x8 __attribute__((ext_vector_type(8)));
typedef short s16x4 __attribute__((ext_vector_type(4)));
typedef float f32x4 __attribute__((ext_vector_type(4)));
typedef float f4 __attribute__((ext_vector_type(4)));
typedef unsigned short u16x4 __attribute__((ext_vector_type(4)));

#define CEXP 14.426950408889634074f   // 10 * log2(e)

__device__ __forceinline__ unsigned short f2bf(float f) {
    union { float f; unsigned int i; } v; v.f = f;
    unsigned int x = v.i;
    return (unsigned short)((x + 0x7fffu + ((x >> 16) & 1u)) >> 16);  // RNE
}
__device__ __forceinline__ float bf2f(unsigned short u) {
    union { unsigned int i; float f; } v; v.i = ((unsigned int)u) << 16; return v.f;
}

__device__ __forceinline__ f32x4 mfma16x16x16_bf16(s16x4 a, s16x4 b, f32x4 c) {
#if __has_builtin(__builtin_amdgcn_mfma_f32_16x16x16bf16_1k)
    return __builtin_amdgcn_mfma_f32_16x16x16bf16_1k(a, b, c, 0, 0, 0);
#else
    f32x4 d = c;
    asm("v_mfma_f32_16x16x16_bf16 %0, %1, %2, %0" : "+v"(d) : "v"(a), "v"(b));
    return d;
#endif
}

// ---------------------------------------------------------------------------
// k_prep: xb = bf16(x); Wt[n][k] = bf16(Wqkv[k][n]); WoT[n][k] = bf16(Wout[k][n])
// blocks 0..1023: x cast (8 elems/thread); 1024..1215: Wt; 1216..1279: WoT.
// ---------------------------------------------------------------------------
__global__ __launch_bounds__(256) void k_prep(
    const float* __restrict__ x, const float* __restrict__ Wqkv,
    const float* __restrict__ Wout,
    unsigned short* __restrict__ xb, unsigned short* __restrict__ Wt,
    unsigned short* __restrict__ WoT)
{
    const int blk = blockIdx.x, tid = threadIdx.x;
    if (blk < 1024) {
        int base = (blk * 256 + tid) * 8;
        f4 a = *(const f4*)&x[base];
        f4 b = *(const f4*)&x[base + 4];
        u16x4 p0 = { f2bf(a[0]), f2bf(a[1]), f2bf(a[2]), f2bf(a[3]) };
        u16x4 p1 = { f2bf(b[0]), f2bf(b[1]), f2bf(b[2]), f2bf(b[3]) };
        *(u16x4*)&xb[base] = p0;
        *(u16x4*)&xb[base + 4] = p1;
    } else if (blk < 1216) {
        int e = (blk - 1024) * 256 + tid;          // e < 49152
        int n = e >> 7, k = e & 127;
        Wt[e] = f2bf(Wqkv[k * 384 + n]);
    } else {
        int e = (blk - 1216) * 256 + tid;          // e < 16384
        int n = e >> 7, k = e & 127;
        WoT[e] = f2bf(Wout[k * 128 + n]);
    }
}

// ---------------------------------------------------------------------------
// k_qkv v2 (MFMA): qkv = x @ W_qkv via bf16 16x16x32 MFMA, K=128 = 4 steps.
// Grid (mt=256, nt=6); block 256 = 4 waves; wave = 16 tokens x 64 cols.
// A (x rows): lane nn -> token, 16B frag.  B (Wt rows = W cols): lane nn ->
// col, 16B frag.  D: row = token = 4*qd+r, col = nn.
// Epilogue: cb<2 -> Qb/Kb [bh][tok][32] scalar bf16 stores + sumsq atomics;
// cb==2 -> Vt [bh][32][tok], u16x4 packed over r (consecutive tokens).
// ---------------------------------------------------------------------------
__global__ __launch_bounds__(256, 4) void k_qkv(
    const unsigned short* __restrict__ xb, const unsigned short* __restrict__ Wt,
    unsigned short* __restrict__ Qb, unsigned short* __restrict__ Kb,
    unsigned short* __restrict__ Vt, float* __restrict__ sumsq)
{
    const int tid = threadIdx.x;
    const int wl = tid >> 6, lane = tid & 63;
    const int qd = lane >> 4, nn = lane & 15;
    const int n0 = blockIdx.y * 64;            // global output col base
    const int tw0 = blockIdx.x * 64 + wl * 16; // token base for this wave

    f32x4 acc[4];
#pragma unroll
    for (int nb = 0; nb < 4; ++nb) acc[nb] = (f32x4){0.f, 0.f, 0.f, 0.f};

    const unsigned short* ap = xb + (size_t)(tw0 + nn) * 128 + qd * 8;
    const unsigned short* bp = Wt + (size_t)(n0 + nn) * 128 + qd * 8;
#pragma unroll
    for (int ks = 0; ks < 4; ++ks) {
        s16x8 af = *(const s16x8*)(ap + ks * 32);
#pragma unroll
        for (int nb = 0; nb < 4; ++nb) {
            s16x8 bf = *(const s16x8*)(bp + (size_t)nb * 16 * 128 + ks * 32);
            acc[nb] = __builtin_amdgcn_mfma_f32_16x16x32_bf16(af, bf, acc[nb], 0, 0, 0);
        }
    }

    const int cb = n0 >> 7;            // 0=q 1=k 2=v
    const int cbase = n0 & 127;        // col base within this cb's 128 dims
    const int b = tw0 >> 12;           // batch
    const int tl0 = tw0 & 4095;        // token within batch

    if (cb < 2) {
        unsigned short* dst = (cb == 0) ? Qb : Kb;
#pragma unroll
        for (int nb = 0; nb < 4; ++nb) {
            const int dim = cbase + nb * 16 + nn;
            const int h = dim >> 5, d = dim & 31;
            unsigned short* base = dst + (size_t)((b * 4 + h) * 4096 + tl0 + qd * 4) * 32 + d;
#pragma unroll
            for (int r = 0; r < 4; ++r)
                base[r * 32] = f2bf(acc[nb][r]);
            float ss = acc[nb][0]*acc[nb][0] + acc[nb][1]*acc[nb][1]
                     + acc[nb][2]*acc[nb][2] + acc[nb][3]*acc[nb][3];
            ss += __shfl_xor(ss, 16);
            ss += __shfl_xor(ss, 32);
            if (qd == 0)
                atomicAdd(&sumsq[cb * 512 + (b * 4 + h) * 32 + d], ss);
        }
    } else {
#pragma unroll
        for (int nb = 0; nb < 4; ++nb) {
            const int dim = cbase + nb * 16 + nn;
            const int h = dim >> 5, d = dim & 31;
            u16x4 pk = { f2bf(acc[nb][0]), f2bf(acc[nb][1]),
                         f2bf(acc[nb][2]), f2bf(acc[nb][3]) };
            *(u16x4*)&Vt[(size_t)((b * 4 + h) * 32 + d) * 4096 + tl0 + qd * 4] = pk;
        }
    }
}

// ---------------------------------------------------------------------------
// k_norm: scale Qb/Kb by min(rsqrt(sumsq), 1e12); Q also gets 10*log2(e).
// ---------------------------------------------------------------------------
__global__ __launch_bounds__(256) void k_norm(
    unsigned short* __restrict__ Qb, unsigned short* __restrict__ Kb,
    const float* __restrict__ sumsq)
{
    int t = blockIdx.x * 256 + threadIdx.x;
    int which = t >> 18;
    int ti = t & 0x3ffff;
    unsigned short* arr = which ? Kb : Qb;
    const float post = which ? 1.0f : CEXP;
    int i8 = ti * 8;
    int d0 = i8 & 31;
    int bh = i8 >> 17;
    const float* sq = sumsq + which * 512 + bh * 32 + d0;
    union { uint4 v; unsigned short u[8]; } dat;
    dat.v = *(const uint4*)(arr + i8);
#pragma unroll
    for (int j = 0; j < 8; ++j) {
        float r = fminf(__builtin_amdgcn_rsqf(sq[j]), 1e12f) * post;
        dat.u[j] = f2bf(bf2f(dat.u[j]) * r);
    }
    *(uint4*)(arr + i8) = dat.v;
}

// ---------------------------------------------------------------------------
// k_attn (R6-validated core): 512 threads = 8 waves; waves 0-3 j in [0,2048),
// waves 4-7 j in [2048,4096); linear merge.  Explicit dwordx4->ds_write_b128
// double-buffered staging, one barrier/iter.  Epilogue now writes Og as BF16
// straight from registers (token=nn, dims 4qd+r) -- no LDS transpose.
// ---------------------------------------------------------------------------
__global__ __launch_bounds__(512, 4) void k_attn(
    const unsigned short* __restrict__ Qb, const unsigned short* __restrict__ Kb,
    const unsigned short* __restrict__ Vt, unsigned short* __restrict__ Ogb)
{
    __shared__ char smem[32768];
    const int tid  = threadIdx.x;
    const int wv   = tid >> 6, lane = tid & 63;
    const int wl   = wv & 3, half = wv >> 2;
    const int qd   = lane >> 4, nn = lane & 15;
    const int bh   = blockIdx.x;
    const int ib   = blockIdx.y * 64 + wl * 16;
    const unsigned short* Qbh = Qb + (size_t)bh * 4096 * 32;
    const unsigned short* Kbh = Kb + (size_t)bh * 4096 * 32;
    const unsigned short* Vbh = Vt + (size_t)bh * 32 * 4096;

    s16x8 qfrag = *(const s16x8*)(Qbh + (ib + nn) * 32 + qd * 8);
    f32x4 o0 = {0.f,0.f,0.f,0.f}, o1 = {0.f,0.f,0.f,0.f};
    const f32x4 zro = {0.f,0.f,0.f,0.f};
    float lp = 0.f;

    const int KB0 = half * 8192;
    const int VB0 = 16384 + half * 8192;
    const int jb0 = half * 2048;

    const unsigned short* ksrc = Kbh + (size_t)(jb0 + wl * 16 + nn) * 32 + qd * 8;
    const unsigned short* vsrc = Vbh + (size_t)(nn + 16 * (wl >> 1)) * 4096
                               + jb0 + ((wl & 1) * 2 + (qd >> 1)) * 16 + (qd & 1) * 8;
    char* kdst = smem + KB0 + wl * 1024 + lane * 16;
    char* vdst = smem + VB0 + wl * 1024 + lane * 16;

    {   // preload tile 0 -> buffer 0
        uint4 gk = *(const uint4*)ksrc;
        uint4 gv = *(const uint4*)vsrc;
        ksrc += 2048; vsrc += 64;
        *(uint4*)kdst = gk;
        *(uint4*)vdst = gv;
    }

    const int vro = (qd >> 1) * 256 + nn * 16 + (qd & 1) * 8;

    for (int jt = 0; jt < 32; ++jt) {
        uint4 ngk = *(const uint4*)ksrc;     // tile jt+1 (jt=31: in-ws, unused)
        uint4 ngv = *(const uint4*)vsrc;
        ksrc += 2048; vsrc += 64;

        __syncthreads();
        const char* kcur = smem + KB0 + (jt & 1) * 4096;
        const char* vcur = smem + VB0 + (jt & 1) * 4096;
#pragma unroll
        for (int js = 0; js < 4; ++js) {
            s16x8 kf = *(const s16x8*)(kcur + js * 1024 + lane * 16);
            f32x4 sv = __builtin_amdgcn_mfma_f32_16x16x32_bf16(kf, qfrag, zro, 0, 0, 0);
            float p0 = __builtin_amdgcn_exp2f(sv[0]);
            float p1 = __builtin_amdgcn_exp2f(sv[1]);
            float p2 = __builtin_amdgcn_exp2f(sv[2]);
            float p3 = __builtin_amdgcn_exp2f(sv[3]);
            lp += (p0 + p1) + (p2 + p3);
            unsigned u0 = __float_as_uint(p0) + 0x8000u;
            unsigned u1 = __float_as_uint(p1) + 0x8000u;
            unsigned u2 = __float_as_uint(p2) + 0x8000u;
            unsigned u3 = __float_as_uint(p3) + 0x8000u;
            union { uint2 u; s16x4 s; } pb;
            pb.u.x = __builtin_amdgcn_perm(u1, u0, 0x07060302u);
            pb.u.y = __builtin_amdgcn_perm(u3, u2, 0x07060302u);
            s16x4 va = *(const s16x4*)(vcur + js * 512 + vro);
            s16x4 vb = *(const s16x4*)(vcur + 2048 + js * 512 + vro);
            o0 = mfma16x16x16_bf16(va, pb.s, o0);
            o1 = mfma16x16x16_bf16(vb, pb.s, o1);
        }
        const int nxt4k = ((jt + 1) & 1) * 4096;
        *(uint4*)(kdst + nxt4k) = ngk;
        *(uint4*)(vdst + nxt4k) = ngv;
    }

    lp += __shfl_xor(lp, 16);
    lp += __shfl_xor(lp, 32);
    __syncthreads();
    float* Ob = (float*)smem;                  // [4][64][8]
    float* Lb = (float*)(smem + 8192);         // [4][64]
    if (half) {
        float* d = Ob + (wl * 64 + lane) * 8;
        *(f4*)d = o0; *(f4*)(d + 4) = o1;
        Lb[wl * 64 + lane] = lp;
    }
    __syncthreads();
    if (!half) {
        float* d = Ob + (wl * 64 + lane) * 8;
        f4 a0 = *(const f4*)d, a1 = *(const f4*)(d + 4);
        float rl = 1.f / (lp + Lb[wl * 64 + lane]);
        o0 = (o0 + a0) * rl;
        o1 = (o1 + a1) * rl;
        u16x4 pk0 = { f2bf(o0[0]), f2bf(o0[1]), f2bf(o0[2]), f2bf(o0[3]) };
        u16x4 pk1 = { f2bf(o1[0]), f2bf(o1[1]), f2bf(o1[2]), f2bf(o1[3]) };
        const int bb = bh >> 2, hh = bh & 3;
        unsigned short* dst = Ogb + (size_t)(bb * 4096 + blockIdx.y * 64 + wl * 16 + nn) * 128
                            + hh * 32 + qd * 4;
        *(u16x4*)dst = pk0;          // dims hh*32 + 4qd + r
        *(u16x4*)(dst + 16) = pk1;   // dims hh*32 + 16 + 4qd + r
    }
}

// ---------------------------------------------------------------------------
// k_out v2 (MFMA): out = Og @ W_out + b_out.  A = WoT rows (outc), B = Og
// rows (tokens): D row = outc = 4qd+r (+nb*16), col = token = nn -> f4-packed
// fp32 stores with bias.  Grid (mt=256, nt=2); block 256 = 4 waves.
// ---------------------------------------------------------------------------
__global__ __launch_bounds__(256, 4) void k_out(
    const unsigned short* __restrict__ Ogb, const unsigned short* __restrict__ WoT,
    const float* __restrict__ bout, float* __restrict__ out)
{
    const int tid = threadIdx.x;
    const int wl = tid >> 6, lane = tid & 63;
    const int qd = lane >> 4, nn = lane & 15;
    const int n0 = blockIdx.y * 64;            // outc base
    const int tw0 = blockIdx.x * 64 + wl * 16; // token base

    f32x4 acc[4];
#pragma unroll
    for (int nb = 0; nb < 4; ++nb) acc[nb] = (f32x4){0.f, 0.f, 0.f, 0.f};

    const unsigned short* ap = WoT + (size_t)(n0 + nn) * 128 + qd * 8;
    const unsigned short* bp = Ogb + (size_t)(tw0 + nn) * 128 + qd * 8;
#pragma unroll
    for (int ks = 0; ks < 4; ++ks) {
        s16x8 bf = *(const s16x8*)(bp + ks * 32);
#pragma unroll
        for (int nb = 0; nb < 4; ++nb) {
            s16x8 af = *(const s16x8*)(ap + (size_t)nb * 16 * 128 + ks * 32);
            acc[nb] = __builtin_amdgcn_mfma_f32_16x16x32_bf16(af, bf, acc[nb], 0, 0, 0);
        }
    }
#pragma unroll
    for (int nb = 0; nb < 4; ++nb) {
        const int c = n0 + nb * 16 + qd * 4;
        f4 bv = *(const f4*)&bout[c];
        f4 r;
#pragma unroll
        for (int j = 0; j < 4; ++j) r[j] = acc[nb][j] + bv[j];
        *(f4*)&out[(size_t)(tw0 + nn) * 128 + c] = r;
    }
}

// ---------------------------------------------------------------------------
extern "C" void kernel_launch(void* const* d_in, const int* in_sizes, int n_in,
                              void* d_out, int out_size, void* d_ws, size_t ws_size,
                              hipStream_t stream)
{
    const float* x    = (const float*)d_in[0];
    const float* Wqkv = (const float*)d_in[1];
    const float* Wout = (const float*)d_in[2];
    const float* bout = (const float*)d_in[3];
    float* out = (float*)d_out;
    char* ws = (char*)d_ws;
    const size_t MB = 1024 * 1024;
    unsigned short* Qb  = (unsigned short*)(ws);             // 4 MB [16][4096][32]
    unsigned short* Kb  = (unsigned short*)(ws + 4 * MB);    // 4 MB
    unsigned short* Vt  = (unsigned short*)(ws + 8 * MB);    // 4 MB [16][32][4096]
    unsigned short* Ogb = (unsigned short*)(ws + 12 * MB);   // 4 MB [16384][128] bf16
    unsigned short* xb  = (unsigned short*)(ws + 16 * MB);   // 4 MB [16384][128] bf16
    unsigned short* Wt  = (unsigned short*)(ws + 20 * MB);            // 96 KB
    unsigned short* WoT = (unsigned short*)(ws + 20 * MB + 112 * 1024); // 32 KB
    float*        sumsq = (float*)(ws + 20 * MB + 160 * 1024);         // 4 KB

    hipMemsetAsync(sumsq, 0, 4096, stream);
    hipLaunchKernelGGL(k_prep, dim3(1280), dim3(256), 0, stream, x, Wqkv, Wout, xb, Wt, WoT);
    hipLaunchKernelGGL(k_qkv, dim3(256, 6), dim3(256), 0, stream, xb, Wt, Qb, Kb, Vt, sumsq);
    hipLaunchKernelGGL(k_norm, dim3(2048), dim3(256), 0, stream, Qb, Kb, sumsq);
    hipLaunchKernelGGL(k_attn, dim3(16, 64), dim3(512), 0, stream, Qb, Kb, Vt, Ogb);
    hipLaunchKernelGGL(k_out, dim3(256, 2), dim3(256), 0, stream, Ogb, WoT, bout, out);
}